// Round 1
// baseline (9.748 us; speedup 1.0000x reference)
//
#include <hip/hip_runtime.h>

#define GLOBAL_AVERAGE 3.5f
#define NUM_FACTORS 64

// One row per 16-lane group: lane j loads float4 #j of the 64-float factor
// rows (coalesced 64B per group per table), rowwise-dot via fma, then a
// 4-step shfl_xor reduce within the 16-lane group. Lane 0 adds biases.
__global__ __launch_bounds__(256) void bmf_predict_kernel(
    const int* __restrict__ users,
    const int* __restrict__ items,
    const float* __restrict__ user_factors,
    const float* __restrict__ item_factors,
    const float* __restrict__ user_biases,
    const float* __restrict__ item_biases,
    float* __restrict__ out,
    int batch)
{
    const int tid  = blockIdx.x * blockDim.x + threadIdx.x;
    const int row  = tid >> 4;   // 16 lanes per batch row
    const int lane = tid & 15;
    if (row >= batch) return;

    const int u = users[row];
    const int it = items[row];

    const float4 a = *reinterpret_cast<const float4*>(
        user_factors + (size_t)u * NUM_FACTORS + lane * 4);
    const float4 b = *reinterpret_cast<const float4*>(
        item_factors + (size_t)it * NUM_FACTORS + lane * 4);

    float p = a.x * b.x;
    p = fmaf(a.y, b.y, p);
    p = fmaf(a.z, b.z, p);
    p = fmaf(a.w, b.w, p);

    // reduce across the 16 lanes of this row's group
    p += __shfl_xor(p, 1, 16);
    p += __shfl_xor(p, 2, 16);
    p += __shfl_xor(p, 4, 16);
    p += __shfl_xor(p, 8, 16);

    if (lane == 0) {
        out[row] = GLOBAL_AVERAGE + user_biases[u] + item_biases[it] + p;
    }
}

extern "C" void kernel_launch(void* const* d_in, const int* in_sizes, int n_in,
                              void* d_out, int out_size, void* d_ws, size_t ws_size,
                              hipStream_t stream)
{
    const int*   users        = (const int*)  d_in[0];
    const int*   items        = (const int*)  d_in[1];
    const float* user_factors = (const float*)d_in[2];
    const float* item_factors = (const float*)d_in[3];
    const float* user_biases  = (const float*)d_in[4];
    const float* item_biases  = (const float*)d_in[5];
    float* out = (float*)d_out;

    const int batch = in_sizes[0];
    const int threads_total = batch * 16;   // 16 lanes per row
    const int block = 256;
    const int grid = (threads_total + block - 1) / block;

    bmf_predict_kernel<<<grid, block, 0, stream>>>(
        users, items, user_factors, item_factors,
        user_biases, item_biases, out, batch);
}